// Round 8
// baseline (881.686 us; speedup 1.0000x reference)
//
#include <hip/hip_runtime.h>

// Problem: B=4096, N=50, D=128, R=3, K=128, 2D=256, RD=768
// out[b,n] = sum_d ao_in[b,n,d] * v[b, s[b,n], d]
//   v[b,r,d] = sum_{d'} ui_in[b,d'] * M[r,d,d'] + c[r,d]
//   M[r,d,d'] = sum_k w_aor[r,d,k] * w_uir[r,d',k]
//   c[r,d]    = sum_k w_aor[r,d,k] * r_param[r,k]
//
// ws layout (floats):
//   v    : [4096][768]   at offset 0
//   w2t  : [768][256]    at 4096*768    row rd=r*256+d, col d'
//   cvec : [768]         after w2t
//
// JOURNAL:
//  r2: vproj reg-staged 64x64 tile, VGPR=184 -> 2 blocks/CU, 89us, VALUBusy 23%.
//  r6: __launch_bounds__(256,3) forced VGPR 84 via SPILLS: WRITE_SIZE 12MB->849MB,
//      FETCH 5MB->499MB, 410-466us. NEVER force occupancy on this structure.
//  r7: global_load_lds(width=16) staging (no reg round-trip) + pre-swizzled
//      global source, linear LDS dest; (256,4) now safe without spills.
//      (unmeasured: broker timeouts r7; resubmitted verbatim)

#define TWO_D 256
#define RD 768

typedef __attribute__((address_space(1))) const unsigned int g_u32;
typedef __attribute__((address_space(3))) unsigned int l_u32;

static __device__ __forceinline__ void gl_lds16(const void* g, void* l) {
    // async global->LDS, 16B per lane; LDS dest = wave-uniform base + lane*16
    __builtin_amdgcn_global_load_lds((g_u32*)g, (l_u32*)l, 16, 0, 0);
}

// ---------------- Kernel A: M + c precompute (GEMM 256x256x128 per r) --------
__global__ __launch_bounds__(256) void relproj_kernel(
    const float* __restrict__ w_aor, const float* __restrict__ w_uir,
    const float* __restrict__ r_param, float* __restrict__ w2t,
    float* __restrict__ cvec)
{
    const int r  = blockIdx.z;
    const int d0 = blockIdx.x * 64;   // m-dim: d   (rows of w_aor[r])
    const int p0 = blockIdx.y * 64;   // n-dim: d'  (rows of w_uir[r])
    const int tid = threadIdx.x;
    const int tx = tid & 15, ty = tid >> 4;

    __shared__ float4 a4[64][16];
    __shared__ float4 b4[64][16];

    float acc[4][4];
#pragma unroll
    for (int i = 0; i < 4; ++i)
#pragma unroll
        for (int j = 0; j < 4; ++j) acc[i][j] = 0.f;

    const float* Am = w_aor + (size_t)r * 256 * 128;
    const float* Bm = w_uir + (size_t)r * 256 * 128;

    for (int ks = 0; ks < 2; ++ks) {
        const int kb = ks * 64;
        __syncthreads();
#pragma unroll
        for (int i = 0; i < 4; ++i) {
            int f = tid + i * 256;          // [0,1024)
            int row = f >> 4, k4 = f & 15;
            int slot = k4 ^ ((row >> 2) & 15);
            a4[row][slot] = *(const float4*)(Am + (size_t)(d0 + row) * 128 + kb + k4 * 4);
            b4[row][slot] = *(const float4*)(Bm + (size_t)(p0 + row) * 128 + kb + k4 * 4);
        }
        __syncthreads();
#pragma unroll
        for (int k4 = 0; k4 < 16; ++k4) {
            float4 av[4], bv[4];
#pragma unroll
            for (int i = 0; i < 4; ++i) { int m = ty * 4 + i; av[i] = a4[m][k4 ^ ((m >> 2) & 15)]; }
#pragma unroll
            for (int j = 0; j < 4; ++j) { int n = tx * 4 + j; bv[j] = b4[n][k4 ^ ((n >> 2) & 15)]; }
#pragma unroll
            for (int i = 0; i < 4; ++i)
#pragma unroll
                for (int j = 0; j < 4; ++j)
                    acc[i][j] += av[i].x * bv[j].x + av[i].y * bv[j].y +
                                 av[i].z * bv[j].z + av[i].w * bv[j].w;
        }
    }

#pragma unroll
    for (int i = 0; i < 4; ++i) {
        int m = ty * 4 + i;                          // d index within tile
        float4 o = make_float4(acc[i][0], acc[i][1], acc[i][2], acc[i][3]);
        *(float4*)(w2t + (size_t)(r * 256 + d0 + m) * 256 + p0 + tx * 4) = o;
    }

    // bias c[r*256+d] computed by blocks with p-tile 0
    if (blockIdx.y == 0 && tid < 64) {
        int d = d0 + tid;
        const float* ar = Am + (size_t)d * 128;
        const float* rp = r_param + r * 128;
        float ssum = 0.f;
#pragma unroll 4
        for (int kk = 0; kk < 128; ++kk) ssum += ar[kk] * rp[kk];
        cvec[r * 256 + d] = ssum;
    }
}

// ---------------- Kernel B: v = ui_in @ w2t^T + c  (4096 x 768 x 256) --------
// v4: global_load_lds(16B) async staging. LDS layout is LINEAR in the write
// order (HW requirement: uniform base + lane*16); the XOR swizzle is applied
// by PRE-SWIZZLING the per-lane GLOBAL source column. Per staging inst i of
// wave w, rows are 16w+4i..16w+4i+3, so (row>>2)&15 == (4w+i)&15 is
// wave-uniform -> col4 = (l&15) ^ ((4w+i)&15). ds_read side identical to r2
// (0 bank conflicts). No reg-staged tiles -> ~100 VGPR, (256,4) safe.
__global__ __launch_bounds__(256, 4) void vproj_kernel(
    const float* __restrict__ u_emb, const float* __restrict__ i_emb,
    const float* __restrict__ w2t, const float* __restrict__ cvec,
    float* __restrict__ v)
{
    const int b0 = blockIdx.x * 64;   // m: batch rows
    const int n0 = blockIdx.y * 64;   // n: rd columns
    const int tid = threadIdx.x;
    const int w = tid >> 6, l = tid & 63;
    const int tx = tid & 15, ty = tid >> 4;

    __shared__ float4 a4[64][16];
    __shared__ float4 b4[64][16];

    // per-lane pre-swizzled source offsets (float units), one per staging inst
    int offA[4], offB[4];
#pragma unroll
    for (int i = 0; i < 4; ++i) {
        const int row = 16 * w + 4 * i + (l >> 4);
        const int c4  = (l & 15) ^ ((4 * w + i) & 15);
        offA[i] = (b0 + row) * 128 + c4 * 4;   // u/i_emb stride 128
        offB[i] = (n0 + row) * 256 + c4 * 4;   // w2t stride 256
    }

    float acc[4][4];
#pragma unroll
    for (int i = 0; i < 4; ++i)
#pragma unroll
        for (int j = 0; j < 4; ++j) acc[i][j] = 0.f;

    for (int ks = 0; ks < 4; ++ks) {
        const float* srcA = ((ks < 2) ? u_emb : i_emb) + (ks & 1) * 64;
        const float* srcB = w2t + ks * 64;
        __syncthreads();   // previous compute done before LDS overwrite
#pragma unroll
        for (int i = 0; i < 4; ++i) {
            gl_lds16(srcA + offA[i], &a4[16 * w + 4 * i][0]);
            gl_lds16(srcB + offB[i], &b4[16 * w + 4 * i][0]);
        }
        __syncthreads();   // drains vmcnt(0): staged data visible
#pragma unroll
        for (int k4 = 0; k4 < 16; ++k4) {
            float4 av[4], bv[4];
#pragma unroll
            for (int i = 0; i < 4; ++i) { int m = ty * 4 + i; av[i] = a4[m][k4 ^ ((m >> 2) & 15)]; }
#pragma unroll
            for (int j = 0; j < 4; ++j) { int n = tx * 4 + j; bv[j] = b4[n][k4 ^ ((n >> 2) & 15)]; }
#pragma unroll
            for (int i = 0; i < 4; ++i)
#pragma unroll
                for (int j = 0; j < 4; ++j)
                    acc[i][j] += av[i].x * bv[j].x + av[i].y * bv[j].y +
                                 av[i].z * bv[j].z + av[i].w * bv[j].w;
        }
    }

    const float4 cb = *(const float4*)(cvec + n0 + tx * 4);
#pragma unroll
    for (int i = 0; i < 4; ++i) {
        int m = ty * 4 + i;
        float4 o = make_float4(acc[i][0] + cb.x, acc[i][1] + cb.y,
                               acc[i][2] + cb.z, acc[i][3] + cb.w);
        *(float4*)(v + (size_t)(b0 + m) * RD + n0 + tx * 4) = o;
    }
}

// ---------------- Kernel C: out[b,n] = dot(ao_in[b,n], v[b, s[b,n]]) ---------
// v3 (unchanged, inferred ~45us): 2 rows per wave; all 12+2 row-loads issued
// BEFORE the LDS staging barrier -> 12-14 outstanding 512B requests per wave.
__global__ __launch_bounds__(256) void score_kernel(
    const float* __restrict__ a_emb, const float* __restrict__ o_emb,
    const float* __restrict__ v, const int* __restrict__ s,
    float* __restrict__ out)
{
    const int b = blockIdx.x;
    const int tid = threadIdx.x;
    const int w = tid >> 6, l = tid & 63;
    const int ll = l & 31, half = l >> 5;
    const size_t rowbase = (size_t)b * 50;

    const float4* a4p = (const float4*)a_emb;
    const float4* o4p = (const float4*)o_emb;

    // rows: pass p in [0,6): n = p*8 + w*2 + half  -> covers 0..47
    float4 xa[6], xo[6];
#pragma unroll
    for (int p = 0; p < 6; ++p) {
        const int n = p * 8 + w * 2 + half;
        const size_t base4 = (rowbase + n) * 32 + ll;
        xa[p] = a4p[base4];
        xo[p] = o4p[base4];
    }
    // leftover rows 48,49 -> wave 0 (half picks the row)
    float4 xa6 = make_float4(0.f, 0.f, 0.f, 0.f);
    float4 xo6 = xa6;
    if (w == 0) {
        const size_t base4 = (rowbase + 48 + half) * 32 + ll;
        xa6 = a4p[base4];
        xo6 = o4p[base4];
    }

    __shared__ float4 v4[192];   // v[b][0..767]
    __shared__ int sl[52];
    if (tid < 192) v4[tid] = ((const float4*)(v + (size_t)b * RD))[tid];
    if (tid < 50) sl[tid] = s[rowbase + tid];
    __syncthreads();

#pragma unroll
    for (int p = 0; p < 6; ++p) {
        const int n = p * 8 + w * 2 + half;
        const int rel = sl[n];
        const float4 va = v4[rel * 64 + ll];
        const float4 vo = v4[rel * 64 + 32 + ll];
        float ps = xa[p].x * va.x + xa[p].y * va.y + xa[p].z * va.z + xa[p].w * va.w
                 + xo[p].x * vo.x + xo[p].y * vo.y + xo[p].z * vo.z + xo[p].w * vo.w;
#pragma unroll
        for (int off = 16; off >= 1; off >>= 1) ps += __shfl_xor(ps, off, 64);
        if (ll == 0) out[rowbase + n] = ps;
    }
    if (w == 0) {
        const int n = 48 + half;
        const int rel = sl[n];
        const float4 va = v4[rel * 64 + ll];
        const float4 vo = v4[rel * 64 + 32 + ll];
        float ps = xa6.x * va.x + xa6.y * va.y + xa6.z * va.z + xa6.w * va.w
                 + xo6.x * vo.x + xo6.y * vo.y + xo6.z * vo.z + xo6.w * vo.w;
#pragma unroll
        for (int off = 16; off >= 1; off >>= 1) ps += __shfl_xor(ps, off, 64);
        if (ll == 0) out[rowbase + n] = ps;
    }
}

extern "C" void kernel_launch(void* const* d_in, const int* in_sizes, int n_in,
                              void* d_out, int out_size, void* d_ws, size_t ws_size,
                              hipStream_t stream)
{
    const float* u_emb   = (const float*)d_in[0];
    const float* i_emb   = (const float*)d_in[1];
    const float* a_emb   = (const float*)d_in[2];
    const float* o_emb   = (const float*)d_in[3];
    const float* w_aor   = (const float*)d_in[4];
    const float* w_uir   = (const float*)d_in[5];
    const float* r_param = (const float*)d_in[6];
    const int*   s       = (const int*)d_in[7];
    float* out = (float*)d_out;

    float* v    = (float*)d_ws;                     // [4096][768]
    float* w2t  = v + (size_t)4096 * RD;            // [768][256]
    float* cvec = w2t + (size_t)RD * TWO_D;         // [768]

    relproj_kernel<<<dim3(4, 4, 3), 256, 0, stream>>>(w_aor, w_uir, r_param, w2t, cvec);
    vproj_kernel<<<dim3(4096 / 64, RD / 64), 256, 0, stream>>>(u_emb, i_emb, w2t, cvec, v);
    score_kernel<<<4096, 256, 0, stream>>>(a_emb, o_emb, v, s, out);
}

// Round 9
// 293.151 us; speedup vs baseline: 3.0076x; 3.0076x over previous
//
#include <hip/hip_runtime.h>

// Problem: B=4096, N=50, D=128, R=3, K=128, 2D=256, RD=768
// out[b,n] = sum_d ao_in[b,n,d] * v[b, s[b,n], d]
//   v[b,r,d] = sum_{d'} ui_in[b,d'] * M[r,d,d'] + c[r,d]
//   M[r,d,d'] = sum_k w_aor[r,d,k] * w_uir[r,d',k]
//   c[r,d]    = sum_k w_aor[r,d,k] * r_param[r,k]
//
// ws layout (floats):
//   v    : [4096][768]   at offset 0
//   w2t  : [768][256]    at 4096*768    row rd=r*256+d, col d'
//   cvec : [768]         after w2t
//
// JOURNAL:
//  r2: vproj reg-staged 64x64 tile (4x4/thread), VGPR=184 -> 2 blocks/CU,
//      89us, VALUBusy 23%, zero spills. Healthy but latency/residency-bound.
//  r6: __launch_bounds__(256,3) forced VGPR 84 via SPILLS: WRITE 12MB->849MB,
//      FETCH 5MB->499MB, 410-466us.
//  r8: global_load_lds + (256,4): WRITE 1.35GB, FETCH 928MB, 670us. Same
//      failure mode. RULE: never force waves/EU below natural pressure on
//      this structure; shrink the tile instead.
//  r9: 64x32 tile, 4x2/thread (staged 6xf4=24, av 16, bv 8, acc 8 -> natural
//      ~140-170 VGPR -> 3 waves/SIMD w/o bounds). 1536 blocks = 2 exact
//      rounds at 3 blocks/CU. No launch_bounds force, no global_load_lds.

#define TWO_D 256
#define RD 768

// ---------------- Kernel A: M + c precompute (GEMM 256x256x128 per r) --------
__global__ __launch_bounds__(256) void relproj_kernel(
    const float* __restrict__ w_aor, const float* __restrict__ w_uir,
    const float* __restrict__ r_param, float* __restrict__ w2t,
    float* __restrict__ cvec)
{
    const int r  = blockIdx.z;
    const int d0 = blockIdx.x * 64;   // m-dim: d   (rows of w_aor[r])
    const int p0 = blockIdx.y * 64;   // n-dim: d'  (rows of w_uir[r])
    const int tid = threadIdx.x;
    const int tx = tid & 15, ty = tid >> 4;

    __shared__ float4 a4[64][16];
    __shared__ float4 b4[64][16];

    float acc[4][4];
#pragma unroll
    for (int i = 0; i < 4; ++i)
#pragma unroll
        for (int j = 0; j < 4; ++j) acc[i][j] = 0.f;

    const float* Am = w_aor + (size_t)r * 256 * 128;
    const float* Bm = w_uir + (size_t)r * 256 * 128;

    for (int ks = 0; ks < 2; ++ks) {
        const int kb = ks * 64;
        __syncthreads();
#pragma unroll
        for (int i = 0; i < 4; ++i) {
            int f = tid + i * 256;          // [0,1024)
            int row = f >> 4, k4 = f & 15;
            int slot = k4 ^ ((row >> 2) & 15);
            a4[row][slot] = *(const float4*)(Am + (size_t)(d0 + row) * 128 + kb + k4 * 4);
            b4[row][slot] = *(const float4*)(Bm + (size_t)(p0 + row) * 128 + kb + k4 * 4);
        }
        __syncthreads();
#pragma unroll
        for (int k4 = 0; k4 < 16; ++k4) {
            float4 av[4], bv[4];
#pragma unroll
            for (int i = 0; i < 4; ++i) { int m = ty * 4 + i; av[i] = a4[m][k4 ^ ((m >> 2) & 15)]; }
#pragma unroll
            for (int j = 0; j < 4; ++j) { int n = tx * 4 + j; bv[j] = b4[n][k4 ^ ((n >> 2) & 15)]; }
#pragma unroll
            for (int i = 0; i < 4; ++i)
#pragma unroll
                for (int j = 0; j < 4; ++j)
                    acc[i][j] += av[i].x * bv[j].x + av[i].y * bv[j].y +
                                 av[i].z * bv[j].z + av[i].w * bv[j].w;
        }
    }

#pragma unroll
    for (int i = 0; i < 4; ++i) {
        int m = ty * 4 + i;                          // d index within tile
        float4 o = make_float4(acc[i][0], acc[i][1], acc[i][2], acc[i][3]);
        *(float4*)(w2t + (size_t)(r * 256 + d0 + m) * 256 + p0 + tx * 4) = o;
    }

    // bias c[r*256+d] computed by blocks with p-tile 0
    if (blockIdx.y == 0 && tid < 64) {
        int d = d0 + tid;
        const float* ar = Am + (size_t)d * 128;
        const float* rp = r_param + r * 128;
        float ssum = 0.f;
#pragma unroll 4
        for (int kk = 0; kk < 128; ++kk) ssum += ar[kk] * rp[kk];
        cvec[r * 256 + d] = ssum;
    }
}

// ---------------- Kernel B: v = ui_in @ w2t^T + c  (4096 x 768 x 256) --------
// v5: 64m x 32n block tile, 256 threads, 4m x 2n per thread. Reg-staged
// (r2's proven path), XOR-swizzled LDS, NO launch_bounds force. Natural
// pressure: staged 6xf4 + av 4xf4 + bv 2xf4 + acc 8 ~= 140-170 VGPR ->
// 3 waves/SIMD -> 3 blocks/CU; grid 1536 = exactly 2 rounds.
__global__ __launch_bounds__(256) void vproj_kernel(
    const float* __restrict__ u_emb, const float* __restrict__ i_emb,
    const float* __restrict__ w2t, const float* __restrict__ cvec,
    float* __restrict__ v)
{
    const int b0 = blockIdx.x * 64;   // m: batch rows
    const int n0 = blockIdx.y * 32;   // n: rd columns
    const int tid = threadIdx.x;
    const int tx = tid & 15, ty = tid >> 4;

    __shared__ float4 a4[64][16];     // 64 rows x 64 floats  (16 KB)
    __shared__ float4 b4[32][16];     // 32 rows x 64 floats  ( 8 KB)

    float acc[4][2];
#pragma unroll
    for (int i = 0; i < 4; ++i) { acc[i][0] = 0.f; acc[i][1] = 0.f; }

    for (int ks = 0; ks < 4; ++ks) {
        const float* srcA = ((ks < 2) ? u_emb : i_emb) + (ks & 1) * 64;
        const float* srcB = w2t + ks * 64;
        __syncthreads();
        // stage A: 1024 float4 = 4/thread
#pragma unroll
        for (int i = 0; i < 4; ++i) {
            int f = tid + i * 256;
            int row = f >> 4, k4 = f & 15;
            a4[row][k4 ^ ((row >> 2) & 15)] =
                *(const float4*)(srcA + (size_t)(b0 + row) * 128 + k4 * 4);
        }
        // stage B: 512 float4 = 2/thread
#pragma unroll
        for (int i = 0; i < 2; ++i) {
            int f = tid + i * 256;
            int row = f >> 4, k4 = f & 15;
            b4[row][k4 ^ ((row >> 2) & 15)] =
                *(const float4*)(srcB + (size_t)(n0 + row) * 256 + k4 * 4);
        }
        __syncthreads();
#pragma unroll
        for (int k4 = 0; k4 < 16; ++k4) {
            float4 av[4], bv[2];
#pragma unroll
            for (int i = 0; i < 4; ++i) { int m = ty * 4 + i; av[i] = a4[m][k4 ^ ((m >> 2) & 15)]; }
#pragma unroll
            for (int j = 0; j < 2; ++j) { int n = tx * 2 + j; bv[j] = b4[n][k4 ^ ((n >> 2) & 15)]; }
#pragma unroll
            for (int i = 0; i < 4; ++i)
#pragma unroll
                for (int j = 0; j < 2; ++j)
                    acc[i][j] += av[i].x * bv[j].x + av[i].y * bv[j].y +
                                 av[i].z * bv[j].z + av[i].w * bv[j].w;
        }
    }

    const float2 cb = *(const float2*)(cvec + n0 + tx * 2);
#pragma unroll
    for (int i = 0; i < 4; ++i) {
        int m = ty * 4 + i;
        float2 o = make_float2(acc[i][0] + cb.x, acc[i][1] + cb.y);
        *(float2*)(v + (size_t)(b0 + m) * RD + n0 + tx * 2) = o;
    }
}

// ---------------- Kernel C: out[b,n] = dot(ao_in[b,n], v[b, s[b,n]]) ---------
// v3 (unchanged): 2 rows per wave; all 12+2 row-loads issued BEFORE the LDS
// staging barrier -> 12-14 outstanding 512B requests per wave.
__global__ __launch_bounds__(256) void score_kernel(
    const float* __restrict__ a_emb, const float* __restrict__ o_emb,
    const float* __restrict__ v, const int* __restrict__ s,
    float* __restrict__ out)
{
    const int b = blockIdx.x;
    const int tid = threadIdx.x;
    const int w = tid >> 6, l = tid & 63;
    const int ll = l & 31, half = l >> 5;
    const size_t rowbase = (size_t)b * 50;

    const float4* a4p = (const float4*)a_emb;
    const float4* o4p = (const float4*)o_emb;

    // rows: pass p in [0,6): n = p*8 + w*2 + half  -> covers 0..47
    float4 xa[6], xo[6];
#pragma unroll
    for (int p = 0; p < 6; ++p) {
        const int n = p * 8 + w * 2 + half;
        const size_t base4 = (rowbase + n) * 32 + ll;
        xa[p] = a4p[base4];
        xo[p] = o4p[base4];
    }
    // leftover rows 48,49 -> wave 0 (half picks the row)
    float4 xa6 = make_float4(0.f, 0.f, 0.f, 0.f);
    float4 xo6 = xa6;
    if (w == 0) {
        const size_t base4 = (rowbase + 48 + half) * 32 + ll;
        xa6 = a4p[base4];
        xo6 = o4p[base4];
    }

    __shared__ float4 v4[192];   // v[b][0..767]
    __shared__ int sl[52];
    if (tid < 192) v4[tid] = ((const float4*)(v + (size_t)b * RD))[tid];
    if (tid < 50) sl[tid] = s[rowbase + tid];
    __syncthreads();

#pragma unroll
    for (int p = 0; p < 6; ++p) {
        const int n = p * 8 + w * 2 + half;
        const int rel = sl[n];
        const float4 va = v4[rel * 64 + ll];
        const float4 vo = v4[rel * 64 + 32 + ll];
        float ps = xa[p].x * va.x + xa[p].y * va.y + xa[p].z * va.z + xa[p].w * va.w
                 + xo[p].x * vo.x + xo[p].y * vo.y + xo[p].z * vo.z + xo[p].w * vo.w;
#pragma unroll
        for (int off = 16; off >= 1; off >>= 1) ps += __shfl_xor(ps, off, 64);
        if (ll == 0) out[rowbase + n] = ps;
    }
    if (w == 0) {
        const int n = 48 + half;
        const int rel = sl[n];
        const float4 va = v4[rel * 64 + ll];
        const float4 vo = v4[rel * 64 + 32 + ll];
        float ps = xa6.x * va.x + xa6.y * va.y + xa6.z * va.z + xa6.w * va.w
                 + xo6.x * vo.x + xo6.y * vo.y + xo6.z * vo.z + xo6.w * vo.w;
#pragma unroll
        for (int off = 16; off >= 1; off >>= 1) ps += __shfl_xor(ps, off, 64);
        if (ll == 0) out[rowbase + n] = ps;
    }
}

extern "C" void kernel_launch(void* const* d_in, const int* in_sizes, int n_in,
                              void* d_out, int out_size, void* d_ws, size_t ws_size,
                              hipStream_t stream)
{
    const float* u_emb   = (const float*)d_in[0];
    const float* i_emb   = (const float*)d_in[1];
    const float* a_emb   = (const float*)d_in[2];
    const float* o_emb   = (const float*)d_in[3];
    const float* w_aor   = (const float*)d_in[4];
    const float* w_uir   = (const float*)d_in[5];
    const float* r_param = (const float*)d_in[6];
    const int*   s       = (const int*)d_in[7];
    float* out = (float*)d_out;

    float* v    = (float*)d_ws;                     // [4096][768]
    float* w2t  = v + (size_t)4096 * RD;            // [768][256]
    float* cvec = w2t + (size_t)RD * TWO_D;         // [768]

    relproj_kernel<<<dim3(4, 4, 3), 256, 0, stream>>>(w_aor, w_uir, r_param, w2t, cvec);
    vproj_kernel<<<dim3(4096 / 64, RD / 32), 256, 0, stream>>>(u_emb, i_emb, w2t, cvec, v);
    score_kernel<<<4096, 256, 0, stream>>>(a_emb, o_emb, v, s, out);
}